// Round 10
// baseline (168.606 us; speedup 1.0000x reference)
//
#include <hip/hip_runtime.h>
#include <stdint.h>

#define Nn 8192
#define Dd 256
#define Ss 4096
#define Cc 65

#define TT 128               // tile size (rows/cols)
#define NTILE 64             // Nn / TT
#define BK 32
#define KS (Dd / BK)         // 8
#define NSLOT 48             // sym path: 16 i-side + 32 j-side lists per row
#define CHUNK 1024           // full path
#define NCHUNK (Nn / CHUNK)  // 8
#define NJT (CHUNK / TT)     // 8

#define BIGF 3.0e37f

typedef float f4 __attribute__((ext_vector_type(4)));
typedef __bf16 bf8 __attribute__((ext_vector_type(8)));

__device__ __forceinline__ float wredsum(float v) {
#pragma unroll
  for (int o = 32; o; o >>= 1) v += __shfl_xor(v, o, 64);
  return v;
}
__device__ __forceinline__ float wredmax(float v) {
#pragma unroll
  for (int o = 32; o; o >>= 1) v = fmaxf(v, __shfl_xor(v, o, 64));
  return v;
}

__device__ __forceinline__ unsigned short f2bf(float f) {
  unsigned int u = __float_as_uint(f);
  u = (u + 0x7fffu + ((u >> 16) & 1u)) >> 16;
  return (unsigned short)u;
}

__device__ __forceinline__ void merge5(const float* a, const float* b, float* o) {
  o[0] = fminf(a[0], b[0]);
  o[1] = fminf(fminf(a[1], b[1]), fmaxf(a[0], b[0]));
  o[2] = fminf(fminf(a[2], b[2]), fminf(fmaxf(a[1], b[0]), fmaxf(a[0], b[1])));
  o[3] = fminf(fminf(a[3], b[3]), fminf(fmaxf(a[2], b[0]), fminf(fmaxf(a[1], b[1]), fmaxf(a[0], b[2]))));
  o[4] = fminf(fminf(a[4], b[4]),
               fminf(fmaxf(a[3], b[0]),
                     fminf(fmaxf(a[2], b[1]), fminf(fmaxf(a[1], b[2]), fmaxf(a[0], b[3])))));
}

__device__ __forceinline__ void mshfl5(float (&a)[5], int off) {
  float b0 = __shfl_xor(a[0], off, 64);
  float b1 = __shfl_xor(a[1], off, 64);
  float b2 = __shfl_xor(a[2], off, 64);
  float b3 = __shfl_xor(a[3], off, 64);
  float b4 = __shfl_xor(a[4], off, 64);
  float c0 = fminf(a[0], b0);
  float c1 = fminf(fminf(a[1], b1), fmaxf(a[0], b0));
  float c2 = fminf(fminf(a[2], b2), fminf(fmaxf(a[1], b0), fmaxf(a[0], b1)));
  float c3 = fminf(fminf(a[3], b3), fminf(fmaxf(a[2], b0), fminf(fmaxf(a[1], b1), fmaxf(a[0], b2))));
  float c4 = fminf(fminf(a[4], b4),
                   fminf(fmaxf(a[3], b0),
                         fminf(fmaxf(a[2], b1), fminf(fmaxf(a[1], b2), fmaxf(a[0], b3)))));
  a[0] = c0; a[1] = c1; a[2] = c2; a[3] = c3; a[4] = c4;
}

__device__ __forceinline__ void ins5(float x, float (&tp)[5]) {
  if (x < tp[4]) {
#pragma unroll
    for (int s2 = 0; s2 < 4; ++s2) {
      float lo = fminf(tp[s2], x);
      x = fmaxf(tp[s2], x);
      tp[s2] = lo;
    }
    tp[4] = x;
  }
}

__device__ __forceinline__ void instile16(const float* tv, float (&tp)[5]) {
  float tm = fminf(fminf(fminf(fminf(tv[0], tv[1]), fminf(tv[2], tv[3])),
                         fminf(fminf(tv[4], tv[5]), fminf(tv[6], tv[7]))),
                   fminf(fminf(fminf(tv[8], tv[9]), fminf(tv[10], tv[11])),
                         fminf(fminf(tv[12], tv[13]), fminf(tv[14], tv[15]))));
  if (tm < tp[4]) {
#pragma unroll
    for (int kk = 0; kk < 16; ++kk) ins5(tv[kk], tp);
  }
}

// ---------------- fused prep (sqn + bf16 cast) + logit losses ----------------
__global__ __launch_bounds__(256) void prep_loss_kernel(const float* __restrict__ X,
                                                        unsigned short* __restrict__ xb,
                                                        float* __restrict__ sqn,
                                                        const float* __restrict__ logit,
                                                        const int* __restrict__ y,
                                                        float* __restrict__ part_cl,
                                                        float* __restrict__ part_ce,
                                                        unsigned int* __restrict__ counter) {
  if (blockIdx.x == 0 && threadIdx.x == 0) *counter = 0u;
  int lane = threadIdx.x & 63;
  if (blockIdx.x < 2048) {
    int row = blockIdx.x * 4 + (threadIdx.x >> 6);
    f4 v = ((const f4*)(X + (size_t)row * Dd))[lane];
    float ss = v[0] * v[0] + v[1] * v[1] + v[2] * v[2] + v[3] * v[3];
    ss = wredsum(ss);
    if (lane == 0) sqn[row] = ss;
    ushort4 o;
    o.x = f2bf(v[0]); o.y = f2bf(v[1]); o.z = f2bf(v[2]); o.w = f2bf(v[3]);
    ((ushort4*)(xb + (size_t)row * Dd))[lane] = o;
  } else {
    int bid = blockIdx.x - 2048;
    int row = bid * 4 + (threadIdx.x >> 6);
    const float* xr = logit + (size_t)row * Cc;
    float x1 = xr[lane];
    float x2 = (lane == 0) ? xr[64] : -BIGF;
    float mx = wredmax(fmaxf(x1, x2));
    float e1 = expf(x1 - mx);
    float e2 = (lane == 0) ? expf(x2 - mx) : 0.f;
    float Z = wredsum(e1 + e2);
    float res;
    if (row < Ss) {
      int yy = y[row];
      float pick = (lane == yy ? x1 : 0.f) + ((lane == 0 && yy == 64) ? x2 : 0.f);
      float xy = wredsum(pick);
      res = -(xy - mx - logf(Z));
    } else {
      float p1 = e1 / Z;
      float t1 = -p1 * log2f(fmaxf(p1, 1e-8f));
      if (lane == 0) {
        float p2 = e2 / Z;
        t1 += -p2 * log2f(fmaxf(p2, 1e-8f));
      }
      res = wredsum(t1);
    }
    __shared__ float a4[4];
    if (lane == 0) a4[threadIdx.x >> 6] = res;
    __syncthreads();
    if (threadIdx.x == 0) {
      float s = a4[0] + a4[1] + a4[2] + a4[3];
      if (bid < 1024) part_cl[bid] = s;
      else part_ce[bid - 1024] = s;
    }
  }
}

__device__ __forceinline__ void stage16(const void* g, void* l) {
  __builtin_amdgcn_global_load_lds((__attribute__((address_space(1))) void*)g,
                                   (__attribute__((address_space(3))) void*)l, 16, 0, 0);
}

// ================= PATH A: symmetric (each Gram tile computed once) =================
// Tile I owns pairs d=(J-I)mod64 in {0..31} (+32 when I<32) -> 2080 pairs.
// 512 blocks (I, strip s): tiles e = s+8t (t=0..3), +e=32 for (s==7, I<32).
// B = I-rows LDS-resident (64 KB); A = J-rows dbuf per-ks (2x8 KB); r2's K-loop.
// i-side: running per-half top5 in regs -> 2 slots/block. j-side: LDS transpose
// (overlay A-dbuf, 4 slices of 32 rows, XOR bank swizzle) -> per-pair slot 15+d.
__global__ __launch_bounds__(512, 4) void dist_sym_kernel(const unsigned short* __restrict__ xb,
                                                          const float* __restrict__ sqn,
                                                          float* __restrict__ top5ws) {
  __shared__ unsigned short ldsB[KS][TT * BK];  // 64 KB resident I-tile
  __shared__ unsigned short ldsA[2][TT * BK];   // 16 KB A dbuf; reused as gbuf/mbuf

  const int tid = threadIdx.x;
  const int lane = tid & 63;
  const int wv = tid >> 6;
  const int q = lane >> 4;
  const int c = lane & 15;
  const int jw = wv & 1;
  const int iq = wv >> 1;

  const int I = blockIdx.x >> 3;
  const int s = blockIdx.x & 7;
  const int Ibase = I * TT;

  const int swz = q ^ ((lane >> 1) & 3);
  const int pr = lane >> 2;
  const int qd = (lane & 3) ^ ((lane >> 3) & 3);
  const int gcol = qd * 8;

  const int nt = (s == 7 && I < 32) ? 5 : 4;

#pragma unroll
  for (int ks = 0; ks < KS; ++ks)
    stage16(xb + (size_t)(Ibase + wv * 16 + pr) * Dd + ks * BK + gcol, &ldsB[ks][wv * 512]);

  const float sqi0 = sqn[Ibase + iq * 32 + c];
  const float sqi1 = sqn[Ibase + iq * 32 + 16 + c];

  float topL[2][5], topH[2][5];
#pragma unroll
  for (int a = 0; a < 2; ++a)
#pragma unroll
    for (int b = 0; b < 5; ++b) { topL[a][b] = BIGF; topH[a][b] = BIGF; }

  float* gbuf = (float*)&ldsA[0][0];

  for (int t = 0; t < nt; ++t) {
    const int e = (t < 4) ? (s + 8 * t) : 32;
    const int J = (I + e) & 63;
    const int Jbase = J * TT;
    const int half = (J >= 32) ? 1 : 0;

    stage16(xb + (size_t)(Jbase + wv * 16 + pr) * Dd + gcol, &ldsA[0][wv * 512]);
    __syncthreads();

    f4 acc[4][2];
    f4 z = {0.f, 0.f, 0.f, 0.f};
#pragma unroll
    for (int a = 0; a < 4; ++a)
#pragma unroll
      for (int b2 = 0; b2 < 2; ++b2) acc[a][b2] = z;

#pragma unroll
    for (int ks = 0; ks < KS; ++ks) {
      if (ks + 1 < KS)
        stage16(xb + (size_t)(Jbase + wv * 16 + pr) * Dd + (ks + 1) * BK + gcol,
                &ldsA[(ks + 1) & 1][wv * 512]);
      bf8 aF[4], bF2[2];
#pragma unroll
      for (int rt = 0; rt < 4; ++rt)
        aF[rt] = *(const bf8*)&ldsA[ks & 1][(jw * 64 + rt * 16 + c) * 32 + swz * 8];
#pragma unroll
      for (int ct = 0; ct < 2; ++ct)
        bF2[ct] = *(const bf8*)&ldsB[ks][(iq * 32 + ct * 16 + c) * 32 + swz * 8];
#pragma unroll
      for (int rt = 0; rt < 4; ++rt)
#pragma unroll
        for (int ct = 0; ct < 2; ++ct)
          acc[rt][ct] = __builtin_amdgcn_mfma_f32_16x16x32_bf16(aF[rt], bF2[ct], acc[rt][ct], 0, 0, 0);
      __syncthreads();
    }

    // i-side: running top5 (key = sqn_j - 2G)
    const int jrow = Jbase + jw * 64;
    f4 sq4[4];
#pragma unroll
    for (int rt = 0; rt < 4; ++rt) sq4[rt] = *(const f4*)&sqn[jrow + rt * 16 + q * 4];
    const bool mayDiag = (e == 0) && ((iq >> 1) == jw);
#pragma unroll
    for (int ct = 0; ct < 2; ++ct) {
      float tv[16];
#pragma unroll
      for (int rt = 0; rt < 4; ++rt)
#pragma unroll
        for (int r = 0; r < 4; ++r)
          tv[rt * 4 + r] = fmaf(acc[rt][ct][r], -2.0f, sq4[rt][r]);
      if (mayDiag && ((c >> 2) == q))
        tv[((iq & 1) * 2 + ct) * 4 + (c & 3)] = BIGF;
      if (half) instile16(tv, topH[ct]);
      else      instile16(tv, topL[ct]);
    }

    // j-side: transpose via LDS, emit per-pair list (key = sqn_i - 2G)
    if (e != 0) {
#pragma unroll
      for (int ss = 0; ss < 4; ++ss) {
        if (jw == (ss >> 1)) {
#pragma unroll
          for (int rt2 = 0; rt2 < 2; ++rt2) {
            const int rt = (ss & 1) * 2 + rt2;
#pragma unroll
            for (int ct2 = 0; ct2 < 2; ++ct2)
#pragma unroll
              for (int r = 0; r < 4; ++r) {
                const int row = rt2 * 16 + q * 4 + r;
                const int col = iq * 32 + ct2 * 16 + c;
                const int pcol = col ^ (((row >> 2) & 3) << 2);
                gbuf[row * 128 + pcol] = fmaf(acc[rt][ct2][r], -2.0f, ct2 ? sqi1 : sqi0);
              }
          }
        }
        __syncthreads();
        const int rr = wv * 4 + (lane >> 4);
        const int X = ((rr >> 2) & 3) << 2;
        f4 v0 = *(const f4*)&gbuf[rr * 128 + ((c * 4) ^ X)];
        f4 v1 = *(const f4*)&gbuf[rr * 128 + 64 + ((c * 4) ^ X)];
        float l5[5] = {BIGF, BIGF, BIGF, BIGF, BIGF};
        ins5(v0[0], l5); ins5(v0[1], l5); ins5(v0[2], l5); ins5(v0[3], l5);
        ins5(v1[0], l5); ins5(v1[1], l5); ins5(v1[2], l5); ins5(v1[3], l5);
        mshfl5(l5, 1); mshfl5(l5, 2); mshfl5(l5, 4); mshfl5(l5, 8);
        if ((lane & 15) == 0) {
          const int jg = Jbase + ss * 32 + rr;
          float* dst = top5ws + ((size_t)jg * NSLOT + 15 + e) * 5;
          dst[0] = l5[0]; dst[1] = l5[1]; dst[2] = l5[2]; dst[3] = l5[3]; dst[4] = l5[4];
        }
        __syncthreads();
      }
    }
  }

  // block-end i-side emit: quad merge + cross-jw merge, slots s*2+half
  float fin[2][2][5];
#pragma unroll
  for (int h = 0; h < 2; ++h)
#pragma unroll
    for (int ct = 0; ct < 2; ++ct) {
#pragma unroll
      for (int k = 0; k < 5; ++k) fin[h][ct][k] = h ? topH[ct][k] : topL[ct][k];
      mshfl5(fin[h][ct], 16);
      mshfl5(fin[h][ct], 32);
    }
  __syncthreads();
  float* mbuf = gbuf;
  if (jw == 1 && q == 0) {
#pragma unroll
    for (int h = 0; h < 2; ++h)
#pragma unroll
      for (int ct = 0; ct < 2; ++ct) {
        float* m = mbuf + (((iq * 2 + ct) * 2 + h) * 16 + c) * 5;
        m[0] = fin[h][ct][0]; m[1] = fin[h][ct][1]; m[2] = fin[h][ct][2];
        m[3] = fin[h][ct][3]; m[4] = fin[h][ct][4];
      }
  }
  __syncthreads();
  if (jw == 0 && q == 0) {
#pragma unroll
    for (int h = 0; h < 2; ++h)
#pragma unroll
      for (int ct = 0; ct < 2; ++ct) {
        const float* m = mbuf + (((iq * 2 + ct) * 2 + h) * 16 + c) * 5;
        float bl[5] = {m[0], m[1], m[2], m[3], m[4]};
        float o[5];
        merge5(fin[h][ct], bl, o);
        const int ii = Ibase + iq * 32 + ct * 16 + c;
        float* dst = top5ws + ((size_t)ii * NSLOT + s * 2 + h) * 5;
        dst[0] = o[0]; dst[1] = o[1]; dst[2] = o[2]; dst[3] = o[3]; dst[4] = o[4];
      }
  }
}

__global__ __launch_bounds__(256) void reg_sym_kernel(const float* __restrict__ top5ws,
                                                      const float* __restrict__ sqn,
                                                      float* __restrict__ part_reg,
                                                      const float* __restrict__ part_cl,
                                                      const float* __restrict__ part_ce,
                                                      float* __restrict__ out,
                                                      unsigned int* __restrict__ counter) {
  int i = blockIdx.x * 256 + threadIdx.x;
  const float* L = top5ws + (size_t)i * (NSLOT * 5);
  float mlo[5], mhi[5];
#pragma unroll
  for (int k = 0; k < 5; ++k) { mlo[k] = BIGF; mhi[k] = BIGF; }
#pragma unroll
  for (int sl = 0; sl < 16; ++sl) {
    const float* p = L + sl * 5;
    float b[5] = {p[0], p[1], p[2], p[3], p[4]};
    float o[5];
    if (sl & 1) { merge5(mhi, b, o); mhi[0]=o[0]; mhi[1]=o[1]; mhi[2]=o[2]; mhi[3]=o[3]; mhi[4]=o[4]; }
    else        { merge5(mlo, b, o); mlo[0]=o[0]; mlo[1]=o[1]; mlo[2]=o[2]; mlo[3]=o[3]; mlo[4]=o[4]; }
  }
  const int R = i >> 7;
  const int nd = (R >= 32) ? 32 : 31;
  for (int d = 1; d <= nd; ++d) {
    const float* p = L + (15 + d) * 5;
    float b[5] = {p[0], p[1], p[2], p[3], p[4]};
    const int It = (R - d + 64) & 63;
    float o[5];
    if (It >= 32) { merge5(mhi, b, o); mhi[0]=o[0]; mhi[1]=o[1]; mhi[2]=o[2]; mhi[3]=o[3]; mhi[4]=o[4]; }
    else          { merge5(mlo, b, o); mlo[0]=o[0]; mlo[1]=o[1]; mlo[2]=o[2]; mlo[3]=o[3]; mlo[4]=o[4]; }
  }
  bool srcRow = (i < Ss);
  float A0 = srcRow ? mlo[0] : mhi[0];
  float A3 = srcRow ? mlo[3] : mhi[3];
  float B0 = srcRow ? mhi[0] : mlo[0];
  float B4 = srcRow ? mhi[4] : mlo[4];
  float sq = sqn[i];
  float dmin_a = sqrtf(fmaxf(A0 + sq, 0.f));
  float kth_a = sqrtf(fmaxf(A3 + sq, 0.f));
  float dmin_b = sqrtf(fmaxf(B0 + sq, 0.f));
  float kth_b = sqrtf(fmaxf(B4 + sq, 0.f));
  float sa = expf(-dmin_a / (2.f * (kth_a + 1e-8f)));
  float sb = expf(-dmin_b / (2.f * (kth_b + 1e-8f)));
  float v = fabsf(sa - sb);
  __shared__ float red[256];
  red[threadIdx.x] = v;
  __syncthreads();
#pragma unroll
  for (int s = 128; s; s >>= 1) {
    if (threadIdx.x < s) red[threadIdx.x] += red[threadIdx.x + s];
    __syncthreads();
  }
  if (threadIdx.x == 0) part_reg[blockIdx.x] = red[0];

  __shared__ unsigned int lastFlag;
  __threadfence();
  if (threadIdx.x == 0) lastFlag = (atomicAdd(counter, 1u) == 31u) ? 1u : 0u;
  __syncthreads();
  if (!lastFlag) return;
  __threadfence();

  __shared__ double dred[256];
  int tid = threadIdx.x;
  double a = 0.0;
  for (int k = tid; k < 1024; k += 256) a += (double)part_cl[k];
  dred[tid] = a; __syncthreads();
  for (int s = 128; s; s >>= 1) { if (tid < s) dred[tid] += dred[tid + s]; __syncthreads(); }
  double cl = dred[0]; __syncthreads();
  a = 0.0;
  for (int k = tid; k < 1024; k += 256) a += (double)part_ce[k];
  dred[tid] = a; __syncthreads();
  for (int s = 128; s; s >>= 1) { if (tid < s) dred[tid] += dred[tid + s]; __syncthreads(); }
  double ce = dred[0]; __syncthreads();
  a = (tid < 16) ? (double)part_reg[tid] : 0.0;
  dred[tid] = a; __syncthreads();
  for (int s = 128; s; s >>= 1) { if (tid < s) dred[tid] += dred[tid + s]; __syncthreads(); }
  double rs = dred[0]; __syncthreads();
  a = (tid >= 16 && tid < 32) ? (double)part_reg[tid] : 0.0;
  dred[tid] = a; __syncthreads();
  for (int s = 128; s; s >>= 1) { if (tid < s) dred[tid] += dred[tid + s]; __syncthreads(); }
  if (tid == 0) {
    out[0] = (float)(cl / 4096.0);
    out[1] = (float)(ce / 4096.0);
    out[2] = (float)(rs / 4096.0 + dred[0] / 4096.0);
  }
}

// ================= PATH B: full-matrix fallback (r2 verbatim, 69.2 us measured) =========
__global__ __launch_bounds__(512, 4) void dist_full_kernel(const unsigned short* __restrict__ xb,
                                                           const float* __restrict__ sqn,
                                                           float* __restrict__ top5ws) {
  __shared__ unsigned short ldsA[2][TT * BK];
  __shared__ unsigned short ldsBf[KS][TT * BK];

  const int tid = threadIdx.x;
  const int lane = tid & 63;
  const int wv = tid >> 6;
  const int q = lane >> 4;
  const int c = lane & 15;
  const int jw = wv & 1;
  const int iq = wv >> 1;

  const int ib = (blockIdx.x / NCHUNK) * TT;
  const int chunk = blockIdx.x % NCHUNK;
  const int jc0 = chunk * CHUNK;

  const int swz = q ^ ((lane >> 1) & 3);
  const int pr = lane >> 2;
  const int qd = (lane & 3) ^ ((lane >> 3) & 3);
  const int gcol = qd * 8;

  float top[2][5];
#pragma unroll
  for (int a = 0; a < 2; ++a)
#pragma unroll
    for (int b = 0; b < 5; ++b) top[a][b] = BIGF;

  const int iwbase = ib + iq * 32;

#pragma unroll
  for (int ks = 0; ks < KS; ++ks)
    stage16(xb + (size_t)(ib + wv * 16 + pr) * Dd + ks * BK + gcol, &ldsBf[ks][wv * 512]);

  for (int jt = 0; jt < NJT; ++jt) {
    const int jb = jc0 + jt * TT;

    f4 acc[4][2];
    f4 z = {0.f, 0.f, 0.f, 0.f};
#pragma unroll
    for (int a = 0; a < 4; ++a)
#pragma unroll
      for (int b2 = 0; b2 < 2; ++b2) acc[a][b2] = z;

    stage16(xb + (size_t)(jb + wv * 16 + pr) * Dd + gcol, &ldsA[0][wv * 512]);
    __syncthreads();

#pragma unroll
    for (int ks = 0; ks < KS; ++ks) {
      const int b = ks & 1;
      if (ks + 1 < KS)
        stage16(xb + (size_t)(jb + wv * 16 + pr) * Dd + (ks + 1) * BK + gcol,
                &ldsA[b ^ 1][wv * 512]);
      bf8 aF[4], bF[2];
#pragma unroll
      for (int rt = 0; rt < 4; ++rt)
        aF[rt] = *(const bf8*)&ldsA[b][(jw * 64 + rt * 16 + c) * 32 + swz * 8];
#pragma unroll
      for (int ct = 0; ct < 2; ++ct)
        bF[ct] = *(const bf8*)&ldsBf[ks][(iq * 32 + ct * 16 + c) * 32 + swz * 8];
#pragma unroll
      for (int rt = 0; rt < 4; ++rt)
#pragma unroll
        for (int ct = 0; ct < 2; ++ct)
          acc[rt][ct] = __builtin_amdgcn_mfma_f32_16x16x32_bf16(aF[rt], bF[ct], acc[rt][ct], 0, 0, 0);
      __syncthreads();
    }

    const int jrow = jb + jw * 64;
    f4 sq4[4];
#pragma unroll
    for (int rt = 0; rt < 4; ++rt) sq4[rt] = *(const f4*)&sqn[jrow + rt * 16 + q * 4];
    const bool mayDiag = (jb == ib) && ((iq >> 1) == jw);
#pragma unroll
    for (int ct = 0; ct < 2; ++ct) {
      float t[16];
#pragma unroll
      for (int rt = 0; rt < 4; ++rt)
#pragma unroll
        for (int r = 0; r < 4; ++r)
          t[rt * 4 + r] = fmaf(acc[rt][ct][r], -2.0f, sq4[rt][r]);
      if (mayDiag && ((c >> 2) == q))
        t[((iq & 1) * 2 + ct) * 4 + (c & 3)] = BIGF;
      instile16(t, top[ct]);
    }
  }

  float fin[2][5];
#pragma unroll
  for (int ct = 0; ct < 2; ++ct) {
#pragma unroll
    for (int k = 0; k < 5; ++k) fin[ct][k] = top[ct][k];
    mshfl5(fin[ct], 16);
    mshfl5(fin[ct], 32);
  }

  float* mbuf = (float*)&ldsA[0][0];
  if (jw == 1 && q == 0) {
#pragma unroll
    for (int ct = 0; ct < 2; ++ct) {
      float* m = mbuf + ((((iq << 1) | ct) << 4) + c) * 5;
      m[0] = fin[ct][0]; m[1] = fin[ct][1]; m[2] = fin[ct][2]; m[3] = fin[ct][3]; m[4] = fin[ct][4];
    }
  }
  __syncthreads();
  if (jw == 0 && q == 0) {
#pragma unroll
    for (int ct = 0; ct < 2; ++ct) {
      const float* m = mbuf + ((((iq << 1) | ct) << 4) + c) * 5;
      float bl[5] = {m[0], m[1], m[2], m[3], m[4]};
      float o[5];
      merge5(fin[ct], bl, o);
      int i = iwbase + ct * 16 + c;
      float* dst = top5ws + ((size_t)i * NCHUNK + chunk) * 5;
      dst[0] = o[0]; dst[1] = o[1]; dst[2] = o[2]; dst[3] = o[3]; dst[4] = o[4];
    }
  }
}

__device__ __forceinline__ void merge4lists(const float* L, float* o) {
  float m01[5], m23[5];
  merge5(L + 0, L + 5, m01);
  merge5(L + 10, L + 15, m23);
  merge5(m01, m23, o);
}

__global__ __launch_bounds__(256) void reg_full_kernel(const float* __restrict__ top5ws,
                                                       const float* __restrict__ sqn,
                                                       float* __restrict__ part_reg,
                                                       const float* __restrict__ part_cl,
                                                       const float* __restrict__ part_ce,
                                                       float* __restrict__ out,
                                                       unsigned int* __restrict__ counter) {
  int i = blockIdx.x * 256 + threadIdx.x;
  float buf[40];
  const float* L = top5ws + (size_t)i * 40;
#pragma unroll
  for (int k = 0; k < 40; ++k) buf[k] = L[k];
  float mlo[5], mhi[5];
  merge4lists(buf, mlo);
  merge4lists(buf + 20, mhi);
  bool srcRow = (i < Ss);
  float A0 = srcRow ? mlo[0] : mhi[0];
  float A3 = srcRow ? mlo[3] : mhi[3];
  float B0 = srcRow ? mhi[0] : mlo[0];
  float B4 = srcRow ? mhi[4] : mlo[4];
  float sq = sqn[i];
  float dmin_a = sqrtf(fmaxf(A0 + sq, 0.f));
  float kth_a = sqrtf(fmaxf(A3 + sq, 0.f));
  float dmin_b = sqrtf(fmaxf(B0 + sq, 0.f));
  float kth_b = sqrtf(fmaxf(B4 + sq, 0.f));
  float sa = expf(-dmin_a / (2.f * (kth_a + 1e-8f)));
  float sb = expf(-dmin_b / (2.f * (kth_b + 1e-8f)));
  float v = fabsf(sa - sb);
  __shared__ float red[256];
  red[threadIdx.x] = v;
  __syncthreads();
#pragma unroll
  for (int s = 128; s; s >>= 1) {
    if (threadIdx.x < s) red[threadIdx.x] += red[threadIdx.x + s];
    __syncthreads();
  }
  if (threadIdx.x == 0) part_reg[blockIdx.x] = red[0];

  __shared__ unsigned int lastFlag;
  __threadfence();
  if (threadIdx.x == 0) lastFlag = (atomicAdd(counter, 1u) == 31u) ? 1u : 0u;
  __syncthreads();
  if (!lastFlag) return;
  __threadfence();

  __shared__ double dred[256];
  int tid = threadIdx.x;
  double a = 0.0;
  for (int k = tid; k < 1024; k += 256) a += (double)part_cl[k];
  dred[tid] = a; __syncthreads();
  for (int s = 128; s; s >>= 1) { if (tid < s) dred[tid] += dred[tid + s]; __syncthreads(); }
  double cl = dred[0]; __syncthreads();
  a = 0.0;
  for (int k = tid; k < 1024; k += 256) a += (double)part_ce[k];
  dred[tid] = a; __syncthreads();
  for (int s = 128; s; s >>= 1) { if (tid < s) dred[tid] += dred[tid + s]; __syncthreads(); }
  double ce = dred[0]; __syncthreads();
  a = (tid < 16) ? (double)part_reg[tid] : 0.0;
  dred[tid] = a; __syncthreads();
  for (int s = 128; s; s >>= 1) { if (tid < s) dred[tid] += dred[tid + s]; __syncthreads(); }
  double rs = dred[0]; __syncthreads();
  a = (tid >= 16 && tid < 32) ? (double)part_reg[tid] : 0.0;
  dred[tid] = a; __syncthreads();
  for (int s = 128; s; s >>= 1) { if (tid < s) dred[tid] += dred[tid + s]; __syncthreads(); }
  if (tid == 0) {
    out[0] = (float)(cl / 4096.0);
    out[1] = (float)(ce / 4096.0);
    out[2] = (float)(rs / 4096.0 + dred[0] / 4096.0);
  }
}

extern "C" void kernel_launch(void* const* d_in, const int* in_sizes, int n_in,
                              void* d_out, int out_size, void* d_ws, size_t ws_size,
                              hipStream_t stream) {
  (void)in_sizes; (void)n_in; (void)out_size;
  const float* X = (const float*)d_in[0];
  const float* logit = (const float*)d_in[1];
  const int* y = (const int*)d_in[2];
  float* out = (float*)d_out;
  char* ws = (char*)d_ws;

  unsigned short* xb = (unsigned short*)ws;               // 4 MB bf16 features
  float* sqn = (float*)(ws + (4u << 20));                 // 32 KB row norms
  float* top5 = (float*)(ws + (4u << 20) + (64u << 10));  // lists

  // Path select: symmetric needs ~13.07 MB of workspace; fall back to the
  // proven full-matrix layout (<= 7.01 MB) if the workspace is smaller.
  const bool sym = (ws_size >= ((size_t)14 << 20));
  const size_t partOff = sym ? ((size_t)13 << 20) : ((size_t)7 << 20);
  float* part_cl = (float*)(ws + partOff);
  float* part_ce = part_cl + 1024;
  float* part_reg = part_ce + 1024;
  unsigned int* counter = (unsigned int*)(part_reg + 32);

  hipLaunchKernelGGL(prep_loss_kernel, dim3(4096), dim3(256), 0, stream, X, xb, sqn, logit, y,
                     part_cl, part_ce, counter);
  if (sym) {
    hipLaunchKernelGGL(dist_sym_kernel, dim3(NTILE * 8), dim3(512), 0, stream, xb, sqn, top5);
    hipLaunchKernelGGL(reg_sym_kernel, dim3(32), dim3(256), 0, stream, top5, sqn, part_reg,
                       part_cl, part_ce, out, counter);
  } else {
    hipLaunchKernelGGL(dist_full_kernel, dim3(NTILE * NCHUNK), dim3(512), 0, stream, xb, sqn, top5);
    hipLaunchKernelGGL(reg_full_kernel, dim3(32), dim3(256), 0, stream, top5, sqn, part_reg,
                       part_cl, part_ce, out, counter);
  }
}